// Round 16
// baseline (4859.226 us; speedup 1.0000x reference)
//
#include <hip/hip_runtime.h>
#include <hip/hip_fp16.h>
#include <cmath>

#define B_ 32
#define S_ 128
#define T_ 64
#define STEPS_ 63
#define V_ 32000
#define E_ 512
#define H_ 512

typedef __attribute__((ext_vector_type(4))) float f32x4;
typedef __attribute__((ext_vector_type(8))) short bf16x8;
typedef __attribute__((ext_vector_type(2))) _Float16 f16x2;

__device__ inline short f2bf(float x) {
  unsigned u = __builtin_bit_cast(unsigned, x);
  u = (u + 0x7fffu + ((u >> 16) & 1u)) >> 16;
  return (short)u;
}
__device__ inline float bf2f(short h) {
  unsigned u = ((unsigned)(unsigned short)h) << 16;
  return __builtin_bit_cast(float, u);
}
__device__ inline float fdot2(__half2 a, __half2 b, float c) {
#if __has_builtin(__builtin_amdgcn_fdot2)
  return __builtin_amdgcn_fdot2(__builtin_bit_cast(f16x2, a),
                                __builtin_bit_cast(f16x2, b), c, false);
#else
  float2 af = __half22float2(a), bf = __half22float2(b);
  return c + af.x * bf.x + af.y * bf.y;
#endif
}
__device__ inline __half2 bc2(unsigned v) { return __builtin_bit_cast(__half2, v); }
__device__ inline float sigm(float x) { return 1.f / (1.f + expf(-x)); }

// ---- pack for batched encoder: W5[u*192 + kq4*3 + g] = 8 halves of
// W[g*512+u][col0 + 8*kq4 .. +8]  (uint4 each) ----------------------------
__global__ __launch_bounds__(256) void k_pack_w5(
    const float* __restrict__ W, int ldw, int col0, uint4* __restrict__ W5) {
  int idx = blockIdx.x * 256 + threadIdx.x;   // 98304 = 512 u * 64 kq4 * 3 g
  int g = idx % 3, kq4 = (idx / 3) & 63, u = idx / 192;
  const float* r = W + (long)(g * 512 + u) * ldw + col0 + 8 * kq4;
  __half h[8];
#pragma unroll
  for (int j = 0; j < 8; ++j) h[j] = __float2half(r[j]);
  W5[idx] = *(uint4*)h;
}

// ---- pack GRU weight trio -> k-paired f16 stream for fdot2 (decoder) -------
__global__ __launch_bounds__(256) void k_pack_w3(
    const float* __restrict__ W, int ldw, int col0, __half* __restrict__ W3) {
  int idx = blockIdx.x * 256 + threadIdx.x;   // 98304 = 128 kq * 3 g * 256 up
  int up = idx & 255, g = (idx >> 8) % 3, kq = idx / 768;
  const float* r0 = W + (long)(g * 512 + 2 * up) * ldw + col0 + 4 * kq;
  const float* r1 = r0 + ldw;
  __half h[8];
  h[0] = __float2half(r0[0]); h[1] = __float2half(r0[1]);
  h[2] = __float2half(r1[0]); h[3] = __float2half(r1[1]);
  h[4] = __float2half(r0[2]); h[5] = __float2half(r0[3]);
  h[6] = __float2half(r1[2]); h[7] = __float2half(r1[3]);
  *(uint4*)(W3 + (long)idx * 8) = *(uint4*)h;
}

// ---- MFMA bf16 split GEMM; outmode: 0 f32, 1 f32+tanh, 2 f16; passes 1|3 ----
__global__ __launch_bounds__(256) void k_mfma_gemm(
    const float* __restrict__ A, const float* __restrict__ emb,
    const int* __restrict__ tok, int amode,
    const float* __restrict__ Bmat, long ldb,
    const float* __restrict__ bias,
    void* __restrict__ outp, long sb, long st,
    int M, int N, int K, int outmode, int passes) {
  __shared__ short Ah[128 * 40];
  __shared__ short Al[128 * 40];
  __shared__ short Bh[128 * 40];
  __shared__ short Bl[128 * 40];
  int t = threadIdx.x;
  int n0 = blockIdx.x * 128, m0 = blockIdx.y * 128;
  int ar = t >> 2, ac = (t & 3) * 8;

  const float* arow0;
  const float* arow1;
  {
    int m = m0 + ar;       int mc = m < M ? m : M - 1;
    int m2 = m0 + ar + 64; int mc2 = m2 < M ? m2 : M - 1;
    if (amode == 0) {
      arow0 = A + (long)mc * K;
      arow1 = A + (long)mc2 * K;
    } else {
      int b = mc & 31, q = mc >> 5;
      int tk = (amode == 1) ? tok[b * S_ + q] : tok[b * T_ + q];
      arow0 = emb + (long)tk * K;
      b = mc2 & 31; q = mc2 >> 5;
      tk = (amode == 1) ? tok[b * S_ + q] : tok[b * T_ + q];
      arow1 = emb + (long)tk * K;
    }
  }
  const float* brow0 = Bmat + (long)(n0 + ar) * ldb;
  const float* brow1 = Bmat + (long)(n0 + ar + 64) * ldb;

  int lane = t & 63, wave = t >> 6;
  int wm = (wave >> 1) * 64, wn = (wave & 1) * 64;
  int lr = lane & 15, lk = lane >> 4;
  f32x4 acc[4][4] = {};

  for (int k0 = 0; k0 < K; k0 += 32) {
    auto stage = [&](const float* rowp, short* Dh, short* Dl, int r) {
      float4 x0 = *(const float4*)(rowp + k0 + ac);
      float4 x1 = *(const float4*)(rowp + k0 + ac + 4);
      float xs[8] = {x0.x, x0.y, x0.z, x0.w, x1.x, x1.y, x1.z, x1.w};
      bf16x8 hi, lo;
#pragma unroll
      for (int i = 0; i < 8; ++i) {
        short h = f2bf(xs[i]);
        hi[i] = h;
        lo[i] = f2bf(xs[i] - bf2f(h));
      }
      *(bf16x8*)&Dh[r * 40 + ac] = hi;
      if (passes > 1) *(bf16x8*)&Dl[r * 40 + ac] = lo;
    };
    stage(arow0, Ah, Al, ar);
    stage(arow1, Ah, Al, ar + 64);
    stage(brow0, Bh, Bl, ar);
    stage(brow1, Bh, Bl, ar + 64);
    __syncthreads();

    bf16x8 a_h[4], b_h[4];
#pragma unroll
    for (int i = 0; i < 4; ++i) {
      a_h[i] = *(const bf16x8*)&Ah[(wm + i * 16 + lr) * 40 + lk * 8];
      b_h[i] = *(const bf16x8*)&Bh[(wn + i * 16 + lr) * 40 + lk * 8];
    }
    if (passes > 1) {
      bf16x8 a_l[4], b_l[4];
#pragma unroll
      for (int i = 0; i < 4; ++i) {
        a_l[i] = *(const bf16x8*)&Al[(wm + i * 16 + lr) * 40 + lk * 8];
        b_l[i] = *(const bf16x8*)&Bl[(wn + i * 16 + lr) * 40 + lk * 8];
      }
#pragma unroll
      for (int i = 0; i < 4; ++i)
#pragma unroll
        for (int j = 0; j < 4; ++j) {
          acc[i][j] = __builtin_amdgcn_mfma_f32_16x16x32_bf16(a_l[i], b_h[j], acc[i][j], 0, 0, 0);
          acc[i][j] = __builtin_amdgcn_mfma_f32_16x16x32_bf16(a_h[i], b_l[j], acc[i][j], 0, 0, 0);
        }
    }
#pragma unroll
    for (int i = 0; i < 4; ++i)
#pragma unroll
      for (int j = 0; j < 4; ++j)
        acc[i][j] = __builtin_amdgcn_mfma_f32_16x16x32_bf16(a_h[i], b_h[j], acc[i][j], 0, 0, 0);
    __syncthreads();
  }

#pragma unroll
  for (int i = 0; i < 4; ++i) {
#pragma unroll
    for (int r = 0; r < 4; ++r) {
      int m = m0 + wm + i * 16 + lk * 4 + r;
      if (m >= M) continue;
      long base = (long)(m & 31) * sb + (long)(m >> 5) * st;
#pragma unroll
      for (int j = 0; j < 4; ++j) {
        int n = n0 + wn + j * 16 + lr;
        float v = acc[i][j][r] + bias[n];
        if (outmode == 2) ((__half*)outp)[base + n] = __float2half(v);
        else ((float*)outp)[base + n] = (outmode == 1) ? tanhf(v) : v;
      }
    }
  }
}

// ---- batched persistent encoder: 16 blocks, block k owns u in [32k,32k+32)
// for ALL 32 b. Weight slice 96KB/step (L2-resident) -> VALU-bound GEMV.
// h exchanged via ping-pong global (agent-scope atomics) + 16 flags.
__global__ __launch_bounds__(1024) void k_enc_all(
    const float* __restrict__ gi_all,      // [S*B][1536], row = s*32+b (bih folded)
    const uint4* __restrict__ W5,          // [u*192 + kq4*3 + g]
    const float* __restrict__ bhh, const int* __restrict__ lens,
    float* __restrict__ h_out,
    __half* __restrict__ EO16,             // [32][128][512] (pre-zeroed)
    float* __restrict__ EO32,              // [4096][512]    (pre-zeroed)
    unsigned* __restrict__ hball,          // [2][32][256] u32(half2), zeroed
    int* __restrict__ flags) {             // [16] (pre-zeroed)
  __shared__ __half2 h_lds[32][257];       // [b][256 half2 + 1 pad]
  __shared__ float gis[3][32][33];
  __shared__ int lenS[32];
  int blk = blockIdx.x, t = threadIdx.x;
  int u_loc = t >> 5, b = t & 31;
  int u0 = blk * 32, u = u0 + u_loc;
  float bhr = bhh[u], bhz = bhh[512 + u], bhn = bhh[1024 + u];
  float hcur = 0.f;
  const uint4* wp = W5 + (long)u * 192;
  if (t < 32) lenS[t] = lens[t];
  int len_b = lens[b];

  for (int s = 0; s < S_; ++s) {
    int par = s & 1;
    if (s > 0) {
      if (t < 16 && t != blk) {
        while (__hip_atomic_load(flags + t, __ATOMIC_ACQUIRE, __HIP_MEMORY_SCOPE_AGENT) < s)
          __builtin_amdgcn_s_sleep(1);
      }
      __syncthreads();
    }
    // stage full h (agent-scope loads) + gi slice
    {
      const unsigned* hb = hball + par * 8192;
#pragma unroll
      for (int j = 0; j < 8; ++j) {
        int idx = j * 1024 + t;
        unsigned v = __hip_atomic_load(hb + idx, __ATOMIC_RELAXED, __HIP_MEMORY_SCOPE_AGENT);
        h_lds[idx >> 8][idx & 255] = bc2(v);
      }
#pragma unroll
      for (int j = 0; j < 3; ++j) {
        int idx = j * 1024 + t;
        int bb = (idx >> 5) & 31, e = idx & 31;
        gis[j][bb][e] = gi_all[((long)s * 32 + bb) * 1536 + j * 512 + u0 + e];
      }
    }
    __syncthreads();
    // GEMV: thread (u_loc, b): 3 gates x 512 k; stride-257 rows conflict-free
    float ar = 0.f, az = 0.f, an = 0.f;
#pragma unroll 8
    for (int kq4 = 0; kq4 < 64; ++kq4) {
      __half2 h0 = h_lds[b][4 * kq4 + 0];
      __half2 h1 = h_lds[b][4 * kq4 + 1];
      __half2 h2 = h_lds[b][4 * kq4 + 2];
      __half2 h3 = h_lds[b][4 * kq4 + 3];
      uint4 wr = wp[kq4 * 3 + 0];
      uint4 wz = wp[kq4 * 3 + 1];
      uint4 wn = wp[kq4 * 3 + 2];
      ar = fdot2(h0, bc2(wr.x), ar); ar = fdot2(h1, bc2(wr.y), ar);
      ar = fdot2(h2, bc2(wr.z), ar); ar = fdot2(h3, bc2(wr.w), ar);
      az = fdot2(h0, bc2(wz.x), az); az = fdot2(h1, bc2(wz.y), az);
      az = fdot2(h2, bc2(wz.z), az); az = fdot2(h3, bc2(wz.w), az);
      an = fdot2(h0, bc2(wn.x), an); an = fdot2(h1, bc2(wn.y), an);
      an = fdot2(h2, bc2(wn.z), an); an = fdot2(h3, bc2(wn.w), an);
    }
    __syncthreads();   // all h_lds reads complete before slice overwrite
    // cell (thread has all 3 gates) + update own h slice in LDS
    {
      bool valid = s < len_b;
      float r = sigm(gis[0][b][u_loc] + ar + bhr);
      float z = sigm(gis[1][b][u_loc] + az + bhz);
      float n = tanhf(gis[2][b][u_loc] + r * (an + bhn));
      float hn = (1.f - z) * n + z * hcur;
      if (valid) hcur = hn;
      ((__half*)&h_lds[b][0])[u] = __float2half(hcur);
    }
    __syncthreads();
    // publish own slice: t<512 -> (bb = t>>4, p = t&15), coalesced 64B runs
    if (t < 512) {
      int bb = t >> 4, p = t & 15;
      __half2 v2 = h_lds[bb][u0 / 2 + p];
      __hip_atomic_store(hball + (par ^ 1) * 8192 + bb * 256 + u0 / 2 + p,
                         __builtin_bit_cast(unsigned, v2),
                         __ATOMIC_RELAXED, __HIP_MEMORY_SCOPE_AGENT);
      if (s < lenS[bb]) {
        long row = (long)bb * 128 + s;
        *(__half2*)(EO16 + row * 512 + u0 + 2 * p) = v2;
        float2 f2 = __half22float2(v2);
        *(float2*)(EO32 + row * 512 + u0 + 2 * p) = f2;
      }
    }
    __syncthreads();
    if (t == 0) {
      __threadfence();
      __hip_atomic_store(flags + blk, s + 1, __ATOMIC_RELEASE, __HIP_MEMORY_SCOPE_AGENT);
    }
  }
  h_out[b * 512 + u] = hcur;
}

// ---- decoder: 32 blocks x 1024 thr; 4-region overlapped step (R13-proven) ---
__global__ __launch_bounds__(1024) void k_dec_all(
    const float* __restrict__ gie,         // [STEPS*B][1536], row = t*32+b
    const __half* __restrict__ EO16g,      // [32][128][512]
    const __half* __restrict__ W3,         // packed Whh_d
    const __half* __restrict__ GV,         // [4096][1536] f16, row = b*128+s
    const float* __restrict__ bhh, const int* __restrict__ lens,
    const float* __restrict__ h_init,
    float* __restrict__ hctx,              // [2016+][1024]: [0:512]=hn [512:1024]=ctx
    float* __restrict__ attns) {
  __shared__ __align__(16) __half2 EOs[32768];   // 128 KB linear [s][c]
  __shared__ __align__(8) __half2 hs16[256];
  __shared__ float pGh[1536];
  __shared__ float pGc[1536];
  __shared__ float gis[1536];
  __shared__ float sc[128];
  int b = blockIdx.x, t = threadIdx.x;
  int lane = t & 63, wave = t >> 6;
  int len = lens[b];
  float br0 = 0, br1 = 0, bz0 = 0, bz1 = 0, bn0 = 0, bn1 = 0, hold0 = 0, hold1 = 0;
  if (t < 256) {
    br0 = bhh[2 * t]; br1 = bhh[2 * t + 1];
    bz0 = bhh[512 + 2 * t]; bz1 = bhh[512 + 2 * t + 1];
    bn0 = bhh[1024 + 2 * t]; bn1 = bhh[1024 + 2 * t + 1];
    float2 h2 = *(const float2*)(h_init + b * 512 + 2 * t);
    hold0 = h2.x; hold1 = h2.y;
    hs16[t] = __float22half2_rn(h2);
  }
  {
    const uint4* src = (const uint4*)(EO16g + (long)b * 128 * 512);
    uint4* dst = (uint4*)EOs;
    for (int i = t; i < 8192; i += 1024) dst[i] = src[i];
  }
  __syncthreads();
  const __half2* GVb = (const __half2*)GV + (long)b * 128 * 768;

  for (int step = 0; step < STEPS_; ++step) {
    long row = (long)step * 32 + b;
    // ---- R1: Whh GEMV (t<768) || raw scores (t>=768) ----
    if (t < 768) {
      int g = t >> 8, up = t & 255;
      const __half* wb = W3 + (long)(g * 256 + up) * 8;
      float a0 = 0.f, a1 = 0.f;
#pragma unroll 8
      for (int kq = 0; kq < 128; ++kq) {
        uint4 w8 = *(const uint4*)(wb + (long)kq * 6144);
        __half2 x01 = hs16[2 * kq], x23 = hs16[2 * kq + 1];
        a0 = fdot2(x01, bc2(w8.x), a0); a1 = fdot2(x01, bc2(w8.y), a1);
        a0 = fdot2(x23, bc2(w8.z), a0); a1 = fdot2(x23, bc2(w8.w), a1);
      }
      pGh[g * 512 + 2 * up] = a0;
      pGh[g * 512 + 2 * up + 1] = a1;
    } else {
      int w = wave - 12;                     // 0..3, each 32 s-rows
      uint4 hv = ((const uint4*)hs16)[lane];
      __half2 h0 = bc2(hv.x), h1 = bc2(hv.y), h2 = bc2(hv.z), h3 = bc2(hv.w);
#pragma unroll 4
      for (int si = 0; si < 32; ++si) {
        int s = w * 32 + si;
        uint4 ev = ((const uint4*)&EOs[s * 256])[lane];
        float p = 0.f;
        p = fdot2(bc2(ev.x), h0, p);
        p = fdot2(bc2(ev.y), h1, p);
        p = fdot2(bc2(ev.z), h2, p);
        p = fdot2(bc2(ev.w), h3, p);
#pragma unroll
        for (int off = 32; off > 0; off >>= 1) p += __shfl_down(p, off, 64);
        if (lane == 0) sc[s] = p;
      }
    }
    __syncthreads();
    // ---- R2: softmax (wave 0) || gis prefetch (t in [64,448)) ----
    if (t < 64) {
      float p0 = sc[lane], p1 = sc[64 + lane];
      bool v0 = lane < len, v1 = 64 + lane < len;
      float m = fmaxf(v0 ? p0 : -INFINITY, v1 ? p1 : -INFINITY);
#pragma unroll
      for (int off = 32; off > 0; off >>= 1) m = fmaxf(m, __shfl_xor(m, off, 64));
      float e0 = v0 ? expf(p0 - m) : 0.f;
      float e1 = v1 ? expf(p1 - m) : 0.f;
      float S = e0 + e1;
#pragma unroll
      for (int off = 32; off > 0; off >>= 1) S += __shfl_xor(S, off, 64);
      float aw0 = e0 / S, aw1 = e1 / S;
      sc[lane] = aw0;
      sc[64 + lane] = aw1;
      float* ap = attns + ((long)b * STEPS_ + step) * 128;
      ap[lane] = aw0;
      ap[64 + lane] = aw1;
    } else if (t < 448) {
      int i0 = (t - 64) * 4;
      *(float4*)(gis + i0) = *(const float4*)(gie + row * 1536 + i0);
    }
    __syncthreads();
    // ---- R3: GV weighted sum (t<768) || ctx from EOs (t>=768) ----
    if (t < 768) {
      float ax = 0.f, ay = 0.f;
      for (int s = 0; s < 128; ++s) {
        if (s == len) break;
        float aw = sc[s];
        float2 g2 = __half22float2(GVb[(long)s * 768 + t]);
        ax += aw * g2.x;
        ay += aw * g2.y;
      }
      pGc[2 * t] = ax;
      pGc[2 * t + 1] = ay;
    } else {
      int c = t - 768;
      float ax = 0.f, ay = 0.f;
      for (int s = 0; s < 128; ++s) {
        if (s == len) break;
        float aw = sc[s];
        float2 e2 = __half22float2(EOs[s * 256 + c]);
        ax += aw * e2.x;
        ay += aw * e2.y;
      }
      *(float2*)(hctx + row * 1024 + 512 + 2 * c) = make_float2(ax, ay);
    }
    __syncthreads();
    // ---- R4: cell (t<256) ----
    if (t < 256) {
      int u0 = 2 * t;
      float r0 = sigm(gis[u0] + pGc[u0] + pGh[u0] + br0);
      float r1 = sigm(gis[u0 + 1] + pGc[u0 + 1] + pGh[u0 + 1] + br1);
      float z0 = sigm(gis[512 + u0] + pGc[512 + u0] + pGh[512 + u0] + bz0);
      float z1 = sigm(gis[512 + u0 + 1] + pGc[512 + u0 + 1] + pGh[512 + u0 + 1] + bz1);
      float n0 = tanhf(gis[1024 + u0] + pGc[1024 + u0] + r0 * (pGh[1024 + u0] + bn0));
      float n1 = tanhf(gis[1024 + u0 + 1] + pGc[1024 + u0 + 1] + r1 * (pGh[1024 + u0 + 1] + bn1));
      hold0 = (1.f - z0) * n0 + z0 * hold0;
      hold1 = (1.f - z1) * n1 + z1 * hold1;
      hs16[t] = __float22half2_rn(make_float2(hold0, hold1));
      *(float2*)(hctx + row * 1024 + u0) = make_float2(hold0, hold1);
    }
    __syncthreads();
  }
}

extern "C" void kernel_launch(void* const* d_in, const int* in_sizes, int n_in,
                              void* d_out, int out_size, void* d_ws, size_t ws_size,
                              hipStream_t stream) {
  (void)in_sizes; (void)n_in; (void)out_size; (void)ws_size;
  const int*   src   = (const int*)d_in[0];
  const int*   lens  = (const int*)d_in[1];
  const int*   tgt   = (const int*)d_in[2];
  const float* emb_e = (const float*)d_in[3];
  const float* Wih_e = (const float*)d_in[4];
  const float* Whh_e = (const float*)d_in[5];
  const float* bih_e = (const float*)d_in[6];
  const float* bhh_e = (const float*)d_in[7];
  const float* emb_d = (const float*)d_in[8];
  const float* Wih_d = (const float*)d_in[9];
  const float* Whh_d = (const float*)d_in[10];
  const float* bih_d = (const float*)d_in[11];
  const float* bhh_d = (const float*)d_in[12];
  const float* Wc    = (const float*)d_in[13];
  const float* bc    = (const float*)d_in[14];
  const float* Wo    = (const float*)d_in[15];
  const float* bo    = (const float*)d_in[16];

  float* logits = (float*)d_out;
  float* attns  = (float*)d_out + (long)B_ * STEPS_ * V_;

  float* w = (float*)d_ws;
  uint4*  W5e  = (uint4*)w;                     // 98304 uint4 (1.5MB)
  __half* W3d  = (__half*)(w + 393216);         // 1.5MB
  float*  zb   = w + 786432;                    // 1536 zeros (GV bias)
  float*  GIe  = w + 788480;                    // 4096 x 1536 f32
  float*  GId  = GIe + 6291456;                 // 2048 x 1536 f32
  __half* EO16 = (__half*)(GId + 3145728);      // 4MB
  float*  EO32 = GId + 3145728 + 1048576;       // 8MB
  float*  h0   = EO32 + 2097152;                // 32 x 512
  unsigned* hball = (unsigned*)(h0 + 16384);    // 2*8192 u32 = 64KB
  int*      flags = (int*)(hball + 16384);      // 16 ints
  // overlays inside GIe (dead after encoder):
  __half* GV    = (__half*)GIe;                 // 4096 x 1536 f16
  float*  hctx  = GIe + 3145728;                // 2048 x 1024 f32
  float*  ccall = GIe + 5242880;                // 2016 x 512 f32

  hipMemsetAsync(EO16, 0, 2097152 * sizeof(__half), stream);
  hipMemsetAsync(EO32, 0, 2097152 * sizeof(float), stream);
  hipMemsetAsync(zb, 0, 1536 * sizeof(float), stream);
  hipMemsetAsync(hball, 0, 16384 * sizeof(unsigned), stream);
  hipMemsetAsync(flags, 0, 16 * sizeof(int), stream);

  k_pack_w5<<<384, 256, 0, stream>>>(Whh_e, 512, 0, W5e);
  k_pack_w3<<<384, 256, 0, stream>>>(Whh_d, 512, 0, W3d);

  // GIe = emb_enc[src] @ Wih_e^T + bih_e   (single-pass bf16)
  k_mfma_gemm<<<dim3(1536 / 128, 4096 / 128), 256, 0, stream>>>(
      nullptr, emb_e, src, 1, Wih_e, 512, bih_e, GIe, 1536L, 32L * 1536L,
      4096, 1536, 512, 0, 1);
  // GId = emb_dec[tgt] @ Wih_d[:, :512]^T + bih_d   (single-pass bf16)
  k_mfma_gemm<<<dim3(1536 / 128, (2016 + 127) / 128), 256, 0, stream>>>(
      nullptr, emb_d, tgt, 2, Wih_d, 1024, bih_d, GId, 1536L, 32L * 1536L,
      2016, 1536, 512, 0, 1);

  k_enc_all<<<16, 1024, 0, stream>>>(GIe, W5e, bhh_e, lens, h0, EO16, EO32,
                                     hball, flags);

  // GV = EO32 @ Wih_d[:,512:1024]^T (f16 out, zero bias, single-pass)
  k_mfma_gemm<<<dim3(1536 / 128, 4096 / 128), 256, 0, stream>>>(
      EO32, nullptr, nullptr, 0, Wih_d + 512, 1024, zb, GV, 1536L, 49152L,
      4096, 1536, 512, 2, 1);

  k_dec_all<<<32, 1024, 0, stream>>>(GId, EO16, W3d, GV, bhh_d, lens, h0,
                                     hctx, attns);

  // cc = tanh([hn|ctx] @ Wc^T + bc) (single-pass)
  k_mfma_gemm<<<dim3(512 / 128, (2016 + 127) / 128), 256, 0, stream>>>(
      hctx, nullptr, nullptr, 0, Wc, 1024, bc, ccall, 512L, 16384L,
      2016, 512, 1024, 1, 1);

  // logits = ccall @ Wo^T + bo (single-pass)
  k_mfma_gemm<<<dim3(V_ / 128, (2016 + 127) / 128), 256, 0, stream>>>(
      ccall, nullptr, nullptr, 0, Wo, 512, bo, logits,
      (long)STEPS_ * V_, (long)V_, 2016, 32000, 512, 0, 1);
}

// Round 17
// 3166.574 us; speedup vs baseline: 1.5345x; 1.5345x over previous
//
#include <hip/hip_runtime.h>
#include <hip/hip_fp16.h>
#include <cmath>

#define B_ 32
#define S_ 128
#define T_ 64
#define STEPS_ 63
#define V_ 32000
#define E_ 512
#define H_ 512

typedef __attribute__((ext_vector_type(4))) float f32x4;
typedef __attribute__((ext_vector_type(8))) short bf16x8;
typedef __attribute__((ext_vector_type(2))) _Float16 f16x2;

__device__ inline short f2bf(float x) {
  unsigned u = __builtin_bit_cast(unsigned, x);
  u = (u + 0x7fffu + ((u >> 16) & 1u)) >> 16;
  return (short)u;
}
__device__ inline float bf2f(short h) {
  unsigned u = ((unsigned)(unsigned short)h) << 16;
  return __builtin_bit_cast(float, u);
}
__device__ inline float fdot2(__half2 a, __half2 b, float c) {
#if __has_builtin(__builtin_amdgcn_fdot2)
  return __builtin_amdgcn_fdot2(__builtin_bit_cast(f16x2, a),
                                __builtin_bit_cast(f16x2, b), c, false);
#else
  float2 af = __half22float2(a), bf = __half22float2(b);
  return c + af.x * bf.x + af.y * bf.y;
#endif
}
__device__ inline __half2 bc2(unsigned v) { return __builtin_bit_cast(__half2, v); }
__device__ inline float sigm(float x) { return 1.f / (1.f + expf(-x)); }

// ---- pack GRU weight trio -> k-paired f16 stream for fdot2 ------------------
__global__ __launch_bounds__(256) void k_pack_w3(
    const float* __restrict__ W, int ldw, int col0, __half* __restrict__ W3) {
  int idx = blockIdx.x * 256 + threadIdx.x;   // 98304 = 128 kq * 3 g * 256 up
  int up = idx & 255, g = (idx >> 8) % 3, kq = idx / 768;
  const float* r0 = W + (long)(g * 512 + 2 * up) * ldw + col0 + 4 * kq;
  const float* r1 = r0 + ldw;
  __half h[8];
  h[0] = __float2half(r0[0]); h[1] = __float2half(r0[1]);
  h[2] = __float2half(r1[0]); h[3] = __float2half(r1[1]);
  h[4] = __float2half(r0[2]); h[5] = __float2half(r0[3]);
  h[6] = __float2half(r1[2]); h[7] = __float2half(r1[3]);
  *(uint4*)(W3 + (long)idx * 8) = *(uint4*)h;
}

// ---- MFMA bf16 split GEMM --------------------------------------------------
// amode: 0 dense f32 A; 1 emb gather via src; 2 emb gather via tgt;
//        3 dense f16 A (A points at __half rows).
// outmode: 0 f32, 1 f32+tanh, 2 f16. passes: 1|3 (hi/lo split precision).
__global__ __launch_bounds__(256) void k_mfma_gemm(
    const float* __restrict__ A, const float* __restrict__ emb,
    const int* __restrict__ tok, int amode,
    const float* __restrict__ Bmat, long ldb,
    const float* __restrict__ bias,
    void* __restrict__ outp, long sb, long st,
    int M, int N, int K, int outmode, int passes) {
  __shared__ short Ah[128 * 40];
  __shared__ short Al[128 * 40];
  __shared__ short Bh[128 * 40];
  __shared__ short Bl[128 * 40];
  int t = threadIdx.x;
  int n0 = blockIdx.x * 128, m0 = blockIdx.y * 128;
  int ar = t >> 2, ac = (t & 3) * 8;

  const float* arow0;
  const float* arow1;
  {
    int m = m0 + ar;       int mc = m < M ? m : M - 1;
    int m2 = m0 + ar + 64; int mc2 = m2 < M ? m2 : M - 1;
    if (amode == 0) {
      arow0 = A + (long)mc * K;
      arow1 = A + (long)mc2 * K;
    } else if (amode == 3) {
      arow0 = (const float*)((const __half*)A + (long)mc * K);
      arow1 = (const float*)((const __half*)A + (long)mc2 * K);
    } else {
      int b = mc & 31, q = mc >> 5;
      int tk = (amode == 1) ? tok[b * S_ + q] : tok[b * T_ + q];
      arow0 = emb + (long)tk * K;
      b = mc2 & 31; q = mc2 >> 5;
      tk = (amode == 1) ? tok[b * S_ + q] : tok[b * T_ + q];
      arow1 = emb + (long)tk * K;
    }
  }
  const float* brow0 = Bmat + (long)(n0 + ar) * ldb;
  const float* brow1 = Bmat + (long)(n0 + ar + 64) * ldb;

  int lane = t & 63, wave = t >> 6;
  int wm = (wave >> 1) * 64, wn = (wave & 1) * 64;
  int lr = lane & 15, lk = lane >> 4;
  f32x4 acc[4][4] = {};

  for (int k0 = 0; k0 < K; k0 += 32) {
    auto pack = [&](const float xs[8], short* Dh, short* Dl, int r) {
      bf16x8 hi, lo;
#pragma unroll
      for (int i = 0; i < 8; ++i) {
        short h = f2bf(xs[i]);
        hi[i] = h;
        lo[i] = f2bf(xs[i] - bf2f(h));
      }
      *(bf16x8*)&Dh[r * 40 + ac] = hi;
      if (passes > 1) *(bf16x8*)&Dl[r * 40 + ac] = lo;
    };
    auto stageA = [&](const float* rowp, int r) {
      float xs[8];
      if (amode == 3) {
        uint4 hv = *(const uint4*)((const __half*)rowp + k0 + ac);
        const __half* hp = (const __half*)&hv;
#pragma unroll
        for (int i = 0; i < 8; ++i) xs[i] = __half2float(hp[i]);
      } else {
        float4 x0 = *(const float4*)(rowp + k0 + ac);
        float4 x1 = *(const float4*)(rowp + k0 + ac + 4);
        xs[0] = x0.x; xs[1] = x0.y; xs[2] = x0.z; xs[3] = x0.w;
        xs[4] = x1.x; xs[5] = x1.y; xs[6] = x1.z; xs[7] = x1.w;
      }
      pack(xs, Ah, Al, r);
    };
    auto stageB = [&](const float* rowp, int r) {
      float xs[8];
      float4 x0 = *(const float4*)(rowp + k0);
      float4 x1 = *(const float4*)(rowp + k0 + 4);
      xs[0] = x0.x; xs[1] = x0.y; xs[2] = x0.z; xs[3] = x0.w;
      xs[4] = x1.x; xs[5] = x1.y; xs[6] = x1.z; xs[7] = x1.w;
      pack(xs, Bh, Bl, r);
    };
    stageA(arow0, ar);
    stageA(arow1, ar + 64);
    stageB(brow0 + ac, ar);
    stageB(brow1 + ac, ar + 64);
    __syncthreads();

    bf16x8 a_h[4], b_h[4];
#pragma unroll
    for (int i = 0; i < 4; ++i) {
      a_h[i] = *(const bf16x8*)&Ah[(wm + i * 16 + lr) * 40 + lk * 8];
      b_h[i] = *(const bf16x8*)&Bh[(wn + i * 16 + lr) * 40 + lk * 8];
    }
    if (passes > 1) {
      bf16x8 a_l[4], b_l[4];
#pragma unroll
      for (int i = 0; i < 4; ++i) {
        a_l[i] = *(const bf16x8*)&Al[(wm + i * 16 + lr) * 40 + lk * 8];
        b_l[i] = *(const bf16x8*)&Bl[(wn + i * 16 + lr) * 40 + lk * 8];
      }
#pragma unroll
      for (int i = 0; i < 4; ++i)
#pragma unroll
        for (int j = 0; j < 4; ++j) {
          acc[i][j] = __builtin_amdgcn_mfma_f32_16x16x32_bf16(a_l[i], b_h[j], acc[i][j], 0, 0, 0);
          acc[i][j] = __builtin_amdgcn_mfma_f32_16x16x32_bf16(a_h[i], b_l[j], acc[i][j], 0, 0, 0);
        }
    }
#pragma unroll
    for (int i = 0; i < 4; ++i)
#pragma unroll
      for (int j = 0; j < 4; ++j)
        acc[i][j] = __builtin_amdgcn_mfma_f32_16x16x32_bf16(a_h[i], b_h[j], acc[i][j], 0, 0, 0);
    __syncthreads();
  }

#pragma unroll
  for (int i = 0; i < 4; ++i) {
#pragma unroll
    for (int r = 0; r < 4; ++r) {
      int m = m0 + wm + i * 16 + lk * 4 + r;
      if (m >= M) continue;
      long base = (long)(m & 31) * sb + (long)(m >> 5) * st;
#pragma unroll
      for (int j = 0; j < 4; ++j) {
        int n = n0 + wn + j * 16 + lr;
        float v = acc[i][j][r] + bias[n];
        if (outmode == 2) ((__half*)outp)[base + n] = __float2half(v);
        else ((float*)outp)[base + n] = (outmode == 1) ? tanhf(v) : v;
      }
    }
  }
}

// ---- encoder: 32 blocks x 1024 thr; 768-thr fdot2 stream (R13-proven) -------
__global__ __launch_bounds__(1024) void k_enc_all(
    const float* __restrict__ gi_all,      // [S*B][1536], row = s*32+b (bih folded)
    const __half* __restrict__ W3,         // packed Whh_e
    const float* __restrict__ bhh, const int* __restrict__ lens,
    float* __restrict__ h_out,
    __half* __restrict__ EO16) {           // [32][128][512] (pre-zeroed)
  __shared__ __align__(8) __half2 hs16[256];
  __shared__ float pGh[1536];
  __shared__ float gis[1536];
  int b = blockIdx.x, t = threadIdx.x;
  int len = lens[b];
  float br0 = 0, br1 = 0, bz0 = 0, bz1 = 0, bn0 = 0, bn1 = 0, hold0 = 0, hold1 = 0;
  if (t < 256) {
    br0 = bhh[2 * t]; br1 = bhh[2 * t + 1];
    bz0 = bhh[512 + 2 * t]; bz1 = bhh[512 + 2 * t + 1];
    bn0 = bhh[1024 + 2 * t]; bn1 = bhh[1024 + 2 * t + 1];
    hs16[t] = __float22half2_rn(make_float2(0.f, 0.f));
  }
  __syncthreads();

  for (int s = 0; s < S_; ++s) {
    if (s == len) break;
    if (t >= 256) {
      int c = t - 256, g = c >> 8, up = c & 255;
      const __half* wb = W3 + (long)(g * 256 + up) * 8;
      float a0 = 0.f, a1 = 0.f;
#pragma unroll 8
      for (int kq = 0; kq < 128; ++kq) {
        uint4 w8 = *(const uint4*)(wb + (long)kq * 6144);
        __half2 x01 = hs16[2 * kq], x23 = hs16[2 * kq + 1];
        a0 = fdot2(x01, bc2(w8.x), a0); a1 = fdot2(x01, bc2(w8.y), a1);
        a0 = fdot2(x23, bc2(w8.z), a0); a1 = fdot2(x23, bc2(w8.w), a1);
      }
      pGh[g * 512 + 2 * up] = a0;
      pGh[g * 512 + 2 * up + 1] = a1;
    } else {
      const float* gi = gi_all + ((long)s * 32 + b) * 1536;
      int i0 = t * 6;
#pragma unroll
      for (int i = 0; i < 6; ++i) gis[i0 + i] = gi[i0 + i];
    }
    __syncthreads();
    if (t < 256) {
      int u0 = 2 * t;
      float r0 = sigm(gis[u0] + pGh[u0] + br0);
      float r1 = sigm(gis[u0 + 1] + pGh[u0 + 1] + br1);
      float z0 = sigm(gis[512 + u0] + pGh[512 + u0] + bz0);
      float z1 = sigm(gis[512 + u0 + 1] + pGh[512 + u0 + 1] + bz1);
      float n0 = tanhf(gis[1024 + u0] + r0 * (pGh[1024 + u0] + bn0));
      float n1 = tanhf(gis[1024 + u0 + 1] + r1 * (pGh[1024 + u0 + 1] + bn1));
      hold0 = (1.f - z0) * n0 + z0 * hold0;
      hold1 = (1.f - z1) * n1 + z1 * hold1;
      __half2 h2 = __float22half2_rn(make_float2(hold0, hold1));
      hs16[t] = h2;
      *(__half2*)(EO16 + ((long)b * 128 + s) * 512 + u0) = h2;
    }
    __syncthreads();
  }
  if (t < 256) *(float2*)(h_out + b * 512 + 2 * t) = make_float2(hold0, hold1);
}

// ---- decoder: 32 blocks x 1024 thr; 4-phase step, softmax hidden ------------
// P1: Whh kq[0,64)   (t<768) || raw scores (t>=768)
// P2: Whh kq[64,128) (t<768) || softmax (wave 12) || gis prefetch (waves 13-15)
// P3: GV-gate sum (t<768) || ctx (t>=768)
// P4: cell (t<256)
__global__ __launch_bounds__(1024) void k_dec_all(
    const float* __restrict__ gie,         // [STEPS*B][1536], row = t*32+b
    const __half* __restrict__ EO16g,      // [32][128][512]
    const __half* __restrict__ W3,         // packed Whh_d
    const __half* __restrict__ GV,         // [4096][1536] f16, row = b*128+s
    const float* __restrict__ bhh, const int* __restrict__ lens,
    const float* __restrict__ h_init,
    float* __restrict__ hctx,              // [2016+][1024]: [0:512]=hn [512:1024]=ctx
    float* __restrict__ attns) {
  __shared__ __align__(16) __half2 EOs[32768];   // 128 KB linear [s][c]
  __shared__ __align__(8) __half2 hs16[256];
  __shared__ float pGh[1536];
  __shared__ float pGc[1536];
  __shared__ float gis[1536];
  __shared__ float sc[128];
  int b = blockIdx.x, t = threadIdx.x;
  int lane = t & 63, wave = t >> 6;
  int len = lens[b];
  float br0 = 0, br1 = 0, bz0 = 0, bz1 = 0, bn0 = 0, bn1 = 0, hold0 = 0, hold1 = 0;
  if (t < 256) {
    br0 = bhh[2 * t]; br1 = bhh[2 * t + 1];
    bz0 = bhh[512 + 2 * t]; bz1 = bhh[512 + 2 * t + 1];
    bn0 = bhh[1024 + 2 * t]; bn1 = bhh[1024 + 2 * t + 1];
    float2 h2 = *(const float2*)(h_init + b * 512 + 2 * t);
    hold0 = h2.x; hold1 = h2.y;
    hs16[t] = __float22half2_rn(h2);
  }
  {
    const uint4* src = (const uint4*)(EO16g + (long)b * 128 * 512);
    uint4* dst = (uint4*)EOs;
    for (int i = t; i < 8192; i += 1024) dst[i] = src[i];
  }
  __syncthreads();
  const __half2* GVb = (const __half2*)GV + (long)b * 128 * 768;

  for (int step = 0; step < STEPS_; ++step) {
    long row = (long)step * 32 + b;
    float a0 = 0.f, a1 = 0.f;
    const __half* wb = nullptr;
    if (t < 768) {
      int g = t >> 8, up = t & 255;
      wb = W3 + (long)(g * 256 + up) * 8;
    }
    // ---- P1: Whh kq[0,64) || raw scores ----
    if (t < 768) {
#pragma unroll 8
      for (int kq = 0; kq < 64; ++kq) {
        uint4 w8 = *(const uint4*)(wb + (long)kq * 6144);
        __half2 x01 = hs16[2 * kq], x23 = hs16[2 * kq + 1];
        a0 = fdot2(x01, bc2(w8.x), a0); a1 = fdot2(x01, bc2(w8.y), a1);
        a0 = fdot2(x23, bc2(w8.z), a0); a1 = fdot2(x23, bc2(w8.w), a1);
      }
    } else {
      int w = wave - 12;                     // 0..3, each 32 s-rows
      uint4 hv = ((const uint4*)hs16)[lane];
      __half2 h0 = bc2(hv.x), h1 = bc2(hv.y), h2 = bc2(hv.z), h3 = bc2(hv.w);
#pragma unroll 4
      for (int si = 0; si < 32; ++si) {
        int s = w * 32 + si;
        uint4 ev = ((const uint4*)&EOs[s * 256])[lane];
        float p = 0.f;
        p = fdot2(bc2(ev.x), h0, p);
        p = fdot2(bc2(ev.y), h1, p);
        p = fdot2(bc2(ev.z), h2, p);
        p = fdot2(bc2(ev.w), h3, p);
#pragma unroll
        for (int off = 32; off > 0; off >>= 1) p += __shfl_down(p, off, 64);
        if (lane == 0) sc[s] = p;
      }
    }
    __syncthreads();
    // ---- P2: Whh kq[64,128) || softmax (wave 12) || gis (waves 13-15) ----
    if (t < 768) {
#pragma unroll 8
      for (int kq = 64; kq < 128; ++kq) {
        uint4 w8 = *(const uint4*)(wb + (long)kq * 6144);
        __half2 x01 = hs16[2 * kq], x23 = hs16[2 * kq + 1];
        a0 = fdot2(x01, bc2(w8.x), a0); a1 = fdot2(x01, bc2(w8.y), a1);
        a0 = fdot2(x23, bc2(w8.z), a0); a1 = fdot2(x23, bc2(w8.w), a1);
      }
      int g = t >> 8, up = t & 255;
      pGh[g * 512 + 2 * up] = a0;
      pGh[g * 512 + 2 * up + 1] = a1;
    } else if (t < 832) {
      int l = t - 768;
      float p0 = sc[l], p1 = sc[64 + l];
      bool v0 = l < len, v1 = 64 + l < len;
      float m = fmaxf(v0 ? p0 : -INFINITY, v1 ? p1 : -INFINITY);
#pragma unroll
      for (int off = 32; off > 0; off >>= 1) m = fmaxf(m, __shfl_xor(m, off, 64));
      float e0 = v0 ? expf(p0 - m) : 0.f;
      float e1 = v1 ? expf(p1 - m) : 0.f;
      float S = e0 + e1;
#pragma unroll
      for (int off = 32; off > 0; off >>= 1) S += __shfl_xor(S, off, 64);
      float aw0 = e0 / S, aw1 = e1 / S;
      sc[l] = aw0;
      sc[64 + l] = aw1;
      float* ap = attns + ((long)b * STEPS_ + step) * 128;
      ap[l] = aw0;
      ap[64 + l] = aw1;
    } else {
      int i0 = (t - 832) * 8;
      const float* gp = gie + row * 1536 + i0;
      *(float4*)(gis + i0) = *(const float4*)(gp);
      *(float4*)(gis + i0 + 4) = *(const float4*)(gp + 4);
    }
    __syncthreads();
    // ---- P3: GV weighted sum (t<768) || ctx from EOs (t>=768) ----
    if (t < 768) {
      float ax = 0.f, ay = 0.f;
      for (int s = 0; s < 128; ++s) {
        if (s == len) break;
        float aw = sc[s];
        float2 g2 = __half22float2(GVb[(long)s * 768 + t]);
        ax += aw * g2.x;
        ay += aw * g2.y;
      }
      pGc[2 * t] = ax;
      pGc[2 * t + 1] = ay;
    } else {
      int c = t - 768;
      float ax = 0.f, ay = 0.f;
      for (int s = 0; s < 128; ++s) {
        if (s == len) break;
        float aw = sc[s];
        float2 e2 = __half22float2(EOs[s * 256 + c]);
        ax += aw * e2.x;
        ay += aw * e2.y;
      }
      *(float2*)(hctx + row * 1024 + 512 + 2 * c) = make_float2(ax, ay);
    }
    __syncthreads();
    // ---- P4: cell (t<256) ----
    if (t < 256) {
      int u0 = 2 * t;
      float r0 = sigm(gis[u0] + pGc[u0] + pGh[u0] + br0);
      float r1 = sigm(gis[u0 + 1] + pGc[u0 + 1] + pGh[u0 + 1] + br1);
      float z0 = sigm(gis[512 + u0] + pGc[512 + u0] + pGh[512 + u0] + bz0);
      float z1 = sigm(gis[512 + u0 + 1] + pGc[512 + u0 + 1] + pGh[512 + u0 + 1] + bz1);
      float n0 = tanhf(gis[1024 + u0] + pGc[1024 + u0] + r0 * (pGh[1024 + u0] + bn0));
      float n1 = tanhf(gis[1024 + u0 + 1] + pGc[1024 + u0 + 1] + r1 * (pGh[1024 + u0 + 1] + bn1));
      hold0 = (1.f - z0) * n0 + z0 * hold0;
      hold1 = (1.f - z1) * n1 + z1 * hold1;
      hs16[t] = __float22half2_rn(make_float2(hold0, hold1));
      *(float2*)(hctx + row * 1024 + u0) = make_float2(hold0, hold1);
    }
    __syncthreads();
  }
}

extern "C" void kernel_launch(void* const* d_in, const int* in_sizes, int n_in,
                              void* d_out, int out_size, void* d_ws, size_t ws_size,
                              hipStream_t stream) {
  (void)in_sizes; (void)n_in; (void)out_size; (void)ws_size;
  const int*   src   = (const int*)d_in[0];
  const int*   lens  = (const int*)d_in[1];
  const int*   tgt   = (const int*)d_in[2];
  const float* emb_e = (const float*)d_in[3];
  const float* Wih_e = (const float*)d_in[4];
  const float* Whh_e = (const float*)d_in[5];
  const float* bih_e = (const float*)d_in[6];
  const float* bhh_e = (const float*)d_in[7];
  const float* emb_d = (const float*)d_in[8];
  const float* Wih_d = (const float*)d_in[9];
  const float* Whh_d = (const float*)d_in[10];
  const float* bih_d = (const float*)d_in[11];
  const float* bhh_d = (const float*)d_in[12];
  const float* Wc    = (const float*)d_in[13];
  const float* bc    = (const float*)d_in[14];
  const float* Wo    = (const float*)d_in[15];
  const float* bo    = (const float*)d_in[16];

  float* logits = (float*)d_out;
  float* attns  = (float*)d_out + (long)B_ * STEPS_ * V_;

  float* w = (float*)d_ws;
  __half* W3e  = (__half*)w;                    // 786432 halves (1.5MB)
  __half* W3d  = (__half*)(w + 393216);         // 1.5MB
  float*  zb   = w + 786432;                    // 1536 zeros (GV bias)
  float*  GIe  = w + 788480;                    // 4096 x 1536 f32
  float*  GId  = GIe + 6291456;                 // 2048 x 1536 f32
  __half* EO16 = (__half*)(GId + 3145728);      // 4MB
  float*  h0   = GId + 3145728 + 1048576;       // 32 x 512
  // overlays inside GIe (dead after encoder):
  __half* GV    = (__half*)GIe;                 // 4096 x 1536 f16
  float*  hctx  = GIe + 3145728;                // 2048 x 1024 f32
  float*  ccall = GIe + 5242880;                // 2016 x 512 f32

  hipMemsetAsync(EO16, 0, 2097152 * sizeof(__half), stream);
  hipMemsetAsync(zb, 0, 1536 * sizeof(float), stream);

  k_pack_w3<<<384, 256, 0, stream>>>(Whh_e, 512, 0, W3e);
  k_pack_w3<<<384, 256, 0, stream>>>(Whh_d, 512, 0, W3d);

  // GIe = emb_enc[src] @ Wih_e^T + bih_e   (single-pass bf16)
  k_mfma_gemm<<<dim3(1536 / 128, 4096 / 128), 256, 0, stream>>>(
      nullptr, emb_e, src, 1, Wih_e, 512, bih_e, GIe, 1536L, 32L * 1536L,
      4096, 1536, 512, 0, 1);
  // GId = emb_dec[tgt] @ Wih_d[:, :512]^T + bih_d   (single-pass bf16)
  k_mfma_gemm<<<dim3(1536 / 128, (2016 + 127) / 128), 256, 0, stream>>>(
      nullptr, emb_d, tgt, 2, Wih_d, 1024, bih_d, GId, 1536L, 32L * 1536L,
      2016, 1536, 512, 0, 1);

  k_enc_all<<<32, 1024, 0, stream>>>(GIe, W3e, bhh_e, lens, h0, EO16);

  // GV = EO16 @ Wih_d[:,512:1024]^T (f16 in/out, zero bias, single-pass)
  k_mfma_gemm<<<dim3(1536 / 128, 4096 / 128), 256, 0, stream>>>(
      (const float*)EO16, nullptr, nullptr, 3, Wih_d + 512, 1024, zb, GV,
      1536L, 49152L, 4096, 1536, 512, 2, 1);

  k_dec_all<<<32, 1024, 0, stream>>>(GId, EO16, W3d, GV, bhh_d, lens, h0,
                                     hctx, attns);

  // cc = tanh([hn|ctx] @ Wc^T + bc) (single-pass)
  k_mfma_gemm<<<dim3(512 / 128, (2016 + 127) / 128), 256, 0, stream>>>(
      hctx, nullptr, nullptr, 0, Wc, 1024, bc, ccall, 512L, 16384L,
      2016, 512, 1024, 1, 1);

  // logits = ccall @ Wo^T + bo (single-pass)
  k_mfma_gemm<<<dim3(V_ / 128, (2016 + 127) / 128), 256, 0, stream>>>(
      ccall, nullptr, nullptr, 0, Wo, 512, bo, logits,
      (long)STEPS_ * V_, (long)V_, 2016, 32000, 512, 0, 1);
}

// Round 18
// 2967.808 us; speedup vs baseline: 1.6373x; 1.0670x over previous
//
#include <hip/hip_runtime.h>
#include <hip/hip_fp16.h>
#include <cmath>

#define B_ 32
#define S_ 128
#define T_ 64
#define STEPS_ 63
#define V_ 32000
#define E_ 512
#define H_ 512

typedef __attribute__((ext_vector_type(4))) float f32x4;
typedef __attribute__((ext_vector_type(8))) short bf16x8;
typedef __attribute__((ext_vector_type(2))) _Float16 f16x2;

__device__ inline short f2bf(float x) {
  unsigned u = __builtin_bit_cast(unsigned, x);
  u = (u + 0x7fffu + ((u >> 16) & 1u)) >> 16;
  return (short)u;
}
__device__ inline float bf2f(short h) {
  unsigned u = ((unsigned)(unsigned short)h) << 16;
  return __builtin_bit_cast(float, u);
}
__device__ inline float fdot2(__half2 a, __half2 b, float c) {
#if __has_builtin(__builtin_amdgcn_fdot2)
  return __builtin_amdgcn_fdot2(__builtin_bit_cast(f16x2, a),
                                __builtin_bit_cast(f16x2, b), c, false);
#else
  float2 af = __half22float2(a), bf = __half22float2(b);
  return c + af.x * bf.x + af.y * bf.y;
#endif
}
__device__ inline __half2 bc2(unsigned v) { return __builtin_bit_cast(__half2, v); }
__device__ inline float sigm(float x) { return 1.f / (1.f + expf(-x)); }

// ---- pack GRU weight trio -> k-paired f16 stream for fdot2 ------------------
__global__ __launch_bounds__(256) void k_pack_w3(
    const float* __restrict__ W, int ldw, int col0, __half* __restrict__ W3) {
  int idx = blockIdx.x * 256 + threadIdx.x;   // 98304 = 128 kq * 3 g * 256 up
  int up = idx & 255, g = (idx >> 8) % 3, kq = idx / 768;
  const float* r0 = W + (long)(g * 512 + 2 * up) * ldw + col0 + 4 * kq;
  const float* r1 = r0 + ldw;
  __half h[8];
  h[0] = __float2half(r0[0]); h[1] = __float2half(r0[1]);
  h[2] = __float2half(r1[0]); h[3] = __float2half(r1[1]);
  h[4] = __float2half(r0[2]); h[5] = __float2half(r0[3]);
  h[6] = __float2half(r1[2]); h[7] = __float2half(r1[3]);
  *(uint4*)(W3 + (long)idx * 8) = *(uint4*)h;
}

// ---- MFMA bf16 split GEMM --------------------------------------------------
// amode: 0 dense f32 A; 1 emb gather via src; 2 emb gather via tgt;
//        3 dense f16 A (A points at __half rows).
// outmode: 0 f32, 1 f32+tanh, 2 f16. passes: 1|3 (hi/lo split precision).
__global__ __launch_bounds__(256) void k_mfma_gemm(
    const float* __restrict__ A, const float* __restrict__ emb,
    const int* __restrict__ tok, int amode,
    const float* __restrict__ Bmat, long ldb,
    const float* __restrict__ bias,
    void* __restrict__ outp, long sb, long st,
    int M, int N, int K, int outmode, int passes) {
  __shared__ short Ah[128 * 40];
  __shared__ short Al[128 * 40];
  __shared__ short Bh[128 * 40];
  __shared__ short Bl[128 * 40];
  int t = threadIdx.x;
  int n0 = blockIdx.x * 128, m0 = blockIdx.y * 128;
  int ar = t >> 2, ac = (t & 3) * 8;

  const float* arow0;
  const float* arow1;
  {
    int m = m0 + ar;       int mc = m < M ? m : M - 1;
    int m2 = m0 + ar + 64; int mc2 = m2 < M ? m2 : M - 1;
    if (amode == 0) {
      arow0 = A + (long)mc * K;
      arow1 = A + (long)mc2 * K;
    } else if (amode == 3) {
      arow0 = (const float*)((const __half*)A + (long)mc * K);
      arow1 = (const float*)((const __half*)A + (long)mc2 * K);
    } else {
      int b = mc & 31, q = mc >> 5;
      int tk = (amode == 1) ? tok[b * S_ + q] : tok[b * T_ + q];
      arow0 = emb + (long)tk * K;
      b = mc2 & 31; q = mc2 >> 5;
      tk = (amode == 1) ? tok[b * S_ + q] : tok[b * T_ + q];
      arow1 = emb + (long)tk * K;
    }
  }
  const float* brow0 = Bmat + (long)(n0 + ar) * ldb;
  const float* brow1 = Bmat + (long)(n0 + ar + 64) * ldb;

  int lane = t & 63, wave = t >> 6;
  int wm = (wave >> 1) * 64, wn = (wave & 1) * 64;
  int lr = lane & 15, lk = lane >> 4;
  f32x4 acc[4][4] = {};

  for (int k0 = 0; k0 < K; k0 += 32) {
    auto pack = [&](const float xs[8], short* Dh, short* Dl, int r) {
      bf16x8 hi, lo;
#pragma unroll
      for (int i = 0; i < 8; ++i) {
        short h = f2bf(xs[i]);
        hi[i] = h;
        lo[i] = f2bf(xs[i] - bf2f(h));
      }
      *(bf16x8*)&Dh[r * 40 + ac] = hi;
      if (passes > 1) *(bf16x8*)&Dl[r * 40 + ac] = lo;
    };
    auto stageA = [&](const float* rowp, int r) {
      float xs[8];
      if (amode == 3) {
        uint4 hv = *(const uint4*)((const __half*)rowp + k0 + ac);
        const __half* hp = (const __half*)&hv;
#pragma unroll
        for (int i = 0; i < 8; ++i) xs[i] = __half2float(hp[i]);
      } else {
        float4 x0 = *(const float4*)(rowp + k0 + ac);
        float4 x1 = *(const float4*)(rowp + k0 + ac + 4);
        xs[0] = x0.x; xs[1] = x0.y; xs[2] = x0.z; xs[3] = x0.w;
        xs[4] = x1.x; xs[5] = x1.y; xs[6] = x1.z; xs[7] = x1.w;
      }
      pack(xs, Ah, Al, r);
    };
    auto stageB = [&](const float* rowp, int r) {
      float xs[8];
      float4 x0 = *(const float4*)(rowp + k0);
      float4 x1 = *(const float4*)(rowp + k0 + 4);
      xs[0] = x0.x; xs[1] = x0.y; xs[2] = x0.z; xs[3] = x0.w;
      xs[4] = x1.x; xs[5] = x1.y; xs[6] = x1.z; xs[7] = x1.w;
      pack(xs, Bh, Bl, r);
    };
    stageA(arow0, ar);
    stageA(arow1, ar + 64);
    stageB(brow0 + ac, ar);
    stageB(brow1 + ac, ar + 64);
    __syncthreads();

    bf16x8 a_h[4], b_h[4];
#pragma unroll
    for (int i = 0; i < 4; ++i) {
      a_h[i] = *(const bf16x8*)&Ah[(wm + i * 16 + lr) * 40 + lk * 8];
      b_h[i] = *(const bf16x8*)&Bh[(wn + i * 16 + lr) * 40 + lk * 8];
    }
    if (passes > 1) {
      bf16x8 a_l[4], b_l[4];
#pragma unroll
      for (int i = 0; i < 4; ++i) {
        a_l[i] = *(const bf16x8*)&Al[(wm + i * 16 + lr) * 40 + lk * 8];
        b_l[i] = *(const bf16x8*)&Bl[(wn + i * 16 + lr) * 40 + lk * 8];
      }
#pragma unroll
      for (int i = 0; i < 4; ++i)
#pragma unroll
        for (int j = 0; j < 4; ++j) {
          acc[i][j] = __builtin_amdgcn_mfma_f32_16x16x32_bf16(a_l[i], b_h[j], acc[i][j], 0, 0, 0);
          acc[i][j] = __builtin_amdgcn_mfma_f32_16x16x32_bf16(a_h[i], b_l[j], acc[i][j], 0, 0, 0);
        }
    }
#pragma unroll
    for (int i = 0; i < 4; ++i)
#pragma unroll
      for (int j = 0; j < 4; ++j)
        acc[i][j] = __builtin_amdgcn_mfma_f32_16x16x32_bf16(a_h[i], b_h[j], acc[i][j], 0, 0, 0);
    __syncthreads();
  }

#pragma unroll
  for (int i = 0; i < 4; ++i) {
#pragma unroll
    for (int r = 0; r < 4; ++r) {
      int m = m0 + wm + i * 16 + lk * 4 + r;
      if (m >= M) continue;
      long base = (long)(m & 31) * sb + (long)(m >> 5) * st;
#pragma unroll
      for (int j = 0; j < 4; ++j) {
        int n = n0 + wn + j * 16 + lr;
        float v = acc[i][j][r] + bias[n];
        if (outmode == 2) ((__half*)outp)[base + n] = __float2half(v);
        else ((float*)outp)[base + n] = (outmode == 1) ? tanhf(v) : v;
      }
    }
  }
}

// ---- encoder: 32 blocks x 1024 thr; 768-thr fdot2 stream (R13/R17-proven) ---
__global__ __launch_bounds__(1024) void k_enc_all(
    const float* __restrict__ gi_all,      // [S*B][1536], row = s*32+b (bih folded)
    const __half* __restrict__ W3,         // packed Whh_e
    const float* __restrict__ bhh, const int* __restrict__ lens,
    float* __restrict__ h_out,
    __half* __restrict__ EO16) {           // [32][128][512] (pre-zeroed)
  __shared__ __align__(8) __half2 hs16[256];
  __shared__ float pGh[1536];
  __shared__ float gis[1536];
  int b = blockIdx.x, t = threadIdx.x;
  int len = lens[b];
  float br0 = 0, br1 = 0, bz0 = 0, bz1 = 0, bn0 = 0, bn1 = 0, hold0 = 0, hold1 = 0;
  if (t < 256) {
    br0 = bhh[2 * t]; br1 = bhh[2 * t + 1];
    bz0 = bhh[512 + 2 * t]; bz1 = bhh[512 + 2 * t + 1];
    bn0 = bhh[1024 + 2 * t]; bn1 = bhh[1024 + 2 * t + 1];
    hs16[t] = __float22half2_rn(make_float2(0.f, 0.f));
  }
  __syncthreads();

  for (int s = 0; s < S_; ++s) {
    if (s == len) break;
    if (t >= 256) {
      int c = t - 256, g = c >> 8, up = c & 255;
      const __half* wb = W3 + (long)(g * 256 + up) * 8;
      float a0 = 0.f, a1 = 0.f;
#pragma unroll 8
      for (int kq = 0; kq < 128; ++kq) {
        uint4 w8 = *(const uint4*)(wb + (long)kq * 6144);
        __half2 x01 = hs16[2 * kq], x23 = hs16[2 * kq + 1];
        a0 = fdot2(x01, bc2(w8.x), a0); a1 = fdot2(x01, bc2(w8.y), a1);
        a0 = fdot2(x23, bc2(w8.z), a0); a1 = fdot2(x23, bc2(w8.w), a1);
      }
      pGh[g * 512 + 2 * up] = a0;
      pGh[g * 512 + 2 * up + 1] = a1;
    } else {
      const float* gi = gi_all + ((long)s * 32 + b) * 1536;
      int i0 = t * 6;
#pragma unroll
      for (int i = 0; i < 6; ++i) gis[i0 + i] = gi[i0 + i];
    }
    __syncthreads();
    if (t < 256) {
      int u0 = 2 * t;
      float r0 = sigm(gis[u0] + pGh[u0] + br0);
      float r1 = sigm(gis[u0 + 1] + pGh[u0 + 1] + br1);
      float z0 = sigm(gis[512 + u0] + pGh[512 + u0] + bz0);
      float z1 = sigm(gis[512 + u0 + 1] + pGh[512 + u0 + 1] + bz1);
      float n0 = tanhf(gis[1024 + u0] + r0 * (pGh[1024 + u0] + bn0));
      float n1 = tanhf(gis[1024 + u0 + 1] + r1 * (pGh[1024 + u0 + 1] + bn1));
      hold0 = (1.f - z0) * n0 + z0 * hold0;
      hold1 = (1.f - z1) * n1 + z1 * hold1;
      __half2 h2 = __float22half2_rn(make_float2(hold0, hold1));
      hs16[t] = h2;
      *(__half2*)(EO16 + ((long)b * 128 + s) * 512 + u0) = h2;
    }
    __syncthreads();
  }
  if (t < 256) *(float2*)(h_out + b * 512 + 2 * t) = make_float2(hold0, hold1);
}

// ---- decoder: 32 blocks x 1024 thr; 4-region overlapped step (R13-proven) ---
// R1: Whh GEMV (waves 0-11) || raw scores (waves 12-15)
// R2: softmax (wave 0)      || gis prefetch
// R3: GV-gate sum (0-11)    || ctx (12-15)
// R4: cell (t<256)
__global__ __launch_bounds__(1024) void k_dec_all(
    const float* __restrict__ gie,         // [STEPS*B][1536], row = t*32+b
    const __half* __restrict__ EO16g,      // [32][128][512]
    const __half* __restrict__ W3,         // packed Whh_d
    const __half* __restrict__ GV,         // [4096][1536] f16, row = b*128+s
    const float* __restrict__ bhh, const int* __restrict__ lens,
    const float* __restrict__ h_init,
    float* __restrict__ hctx,              // [2016+][1024]: [0:512]=hn [512:1024]=ctx
    float* __restrict__ attns) {
  __shared__ __align__(16) __half2 EOs[32768];   // 128 KB linear [s][c]
  __shared__ __align__(8) __half2 hs16[256];
  __shared__ float pGh[1536];
  __shared__ float pGc[1536];
  __shared__ float gis[1536];
  __shared__ float sc[128];
  int b = blockIdx.x, t = threadIdx.x;
  int lane = t & 63, wave = t >> 6;
  int len = lens[b];
  float br0 = 0, br1 = 0, bz0 = 0, bz1 = 0, bn0 = 0, bn1 = 0, hold0 = 0, hold1 = 0;
  if (t < 256) {
    br0 = bhh[2 * t]; br1 = bhh[2 * t + 1];
    bz0 = bhh[512 + 2 * t]; bz1 = bhh[512 + 2 * t + 1];
    bn0 = bhh[1024 + 2 * t]; bn1 = bhh[1024 + 2 * t + 1];
    float2 h2 = *(const float2*)(h_init + b * 512 + 2 * t);
    hold0 = h2.x; hold1 = h2.y;
    hs16[t] = __float22half2_rn(h2);
  }
  {
    const uint4* src = (const uint4*)(EO16g + (long)b * 128 * 512);
    uint4* dst = (uint4*)EOs;
    for (int i = t; i < 8192; i += 1024) dst[i] = src[i];
  }
  __syncthreads();
  const __half2* GVb = (const __half2*)GV + (long)b * 128 * 768;

  for (int step = 0; step < STEPS_; ++step) {
    long row = (long)step * 32 + b;
    // ---- R1: Whh GEMV (t<768) || raw scores (t>=768) ----
    if (t < 768) {
      int g = t >> 8, up = t & 255;
      const __half* wb = W3 + (long)(g * 256 + up) * 8;
      float a0 = 0.f, a1 = 0.f;
#pragma unroll 8
      for (int kq = 0; kq < 128; ++kq) {
        uint4 w8 = *(const uint4*)(wb + (long)kq * 6144);
        __half2 x01 = hs16[2 * kq], x23 = hs16[2 * kq + 1];
        a0 = fdot2(x01, bc2(w8.x), a0); a1 = fdot2(x01, bc2(w8.y), a1);
        a0 = fdot2(x23, bc2(w8.z), a0); a1 = fdot2(x23, bc2(w8.w), a1);
      }
      pGh[g * 512 + 2 * up] = a0;
      pGh[g * 512 + 2 * up + 1] = a1;
    } else {
      int w = wave - 12;                     // 0..3, each 32 s-rows
      uint4 hv = ((const uint4*)hs16)[lane];
      __half2 h0 = bc2(hv.x), h1 = bc2(hv.y), h2 = bc2(hv.z), h3 = bc2(hv.w);
#pragma unroll 4
      for (int si = 0; si < 32; ++si) {
        int s = w * 32 + si;
        uint4 ev = ((const uint4*)&EOs[s * 256])[lane];
        float p = 0.f;
        p = fdot2(bc2(ev.x), h0, p);
        p = fdot2(bc2(ev.y), h1, p);
        p = fdot2(bc2(ev.z), h2, p);
        p = fdot2(bc2(ev.w), h3, p);
#pragma unroll
        for (int off = 32; off > 0; off >>= 1) p += __shfl_down(p, off, 64);
        if (lane == 0) sc[s] = p;
      }
    }
    __syncthreads();
    // ---- R2: softmax (wave 0) || gis prefetch (t in [64,448)) ----
    if (t < 64) {
      float p0 = sc[lane], p1 = sc[64 + lane];
      bool v0 = lane < len, v1 = 64 + lane < len;
      float m = fmaxf(v0 ? p0 : -INFINITY, v1 ? p1 : -INFINITY);
#pragma unroll
      for (int off = 32; off > 0; off >>= 1) m = fmaxf(m, __shfl_xor(m, off, 64));
      float e0 = v0 ? expf(p0 - m) : 0.f;
      float e1 = v1 ? expf(p1 - m) : 0.f;
      float S = e0 + e1;
#pragma unroll
      for (int off = 32; off > 0; off >>= 1) S += __shfl_xor(S, off, 64);
      float aw0 = e0 / S, aw1 = e1 / S;
      sc[lane] = aw0;
      sc[64 + lane] = aw1;
      float* ap = attns + ((long)b * STEPS_ + step) * 128;
      ap[lane] = aw0;
      ap[64 + lane] = aw1;
    } else if (t < 448) {
      int i0 = (t - 64) * 4;
      *(float4*)(gis + i0) = *(const float4*)(gie + row * 1536 + i0);
    }
    __syncthreads();
    // ---- R3: GV weighted sum (t<768) || ctx from EOs (t>=768) ----
    if (t < 768) {
      float ax = 0.f, ay = 0.f;
      for (int s = 0; s < 128; ++s) {
        if (s == len) break;
        float aw = sc[s];
        float2 g2 = __half22float2(GVb[(long)s * 768 + t]);
        ax += aw * g2.x;
        ay += aw * g2.y;
      }
      pGc[2 * t] = ax;
      pGc[2 * t + 1] = ay;
    } else {
      int c = t - 768;
      float ax = 0.f, ay = 0.f;
      for (int s = 0; s < 128; ++s) {
        if (s == len) break;
        float aw = sc[s];
        float2 e2 = __half22float2(EOs[s * 256 + c]);
        ax += aw * e2.x;
        ay += aw * e2.y;
      }
      *(float2*)(hctx + row * 1024 + 512 + 2 * c) = make_float2(ax, ay);
    }
    __syncthreads();
    // ---- R4: cell (t<256) ----
    if (t < 256) {
      int u0 = 2 * t;
      float r0 = sigm(gis[u0] + pGc[u0] + pGh[u0] + br0);
      float r1 = sigm(gis[u0 + 1] + pGc[u0 + 1] + pGh[u0 + 1] + br1);
      float z0 = sigm(gis[512 + u0] + pGc[512 + u0] + pGh[512 + u0] + bz0);
      float z1 = sigm(gis[512 + u0 + 1] + pGc[512 + u0 + 1] + pGh[512 + u0 + 1] + bz1);
      float n0 = tanhf(gis[1024 + u0] + pGc[1024 + u0] + r0 * (pGh[1024 + u0] + bn0));
      float n1 = tanhf(gis[1024 + u0 + 1] + pGc[1024 + u0 + 1] + r1 * (pGh[1024 + u0 + 1] + bn1));
      hold0 = (1.f - z0) * n0 + z0 * hold0;
      hold1 = (1.f - z1) * n1 + z1 * hold1;
      hs16[t] = __float22half2_rn(make_float2(hold0, hold1));
      *(float2*)(hctx + row * 1024 + u0) = make_float2(hold0, hold1);
    }
    __syncthreads();
  }
}

extern "C" void kernel_launch(void* const* d_in, const int* in_sizes, int n_in,
                              void* d_out, int out_size, void* d_ws, size_t ws_size,
                              hipStream_t stream) {
  (void)in_sizes; (void)n_in; (void)out_size; (void)ws_size;
  const int*   src   = (const int*)d_in[0];
  const int*   lens  = (const int*)d_in[1];
  const int*   tgt   = (const int*)d_in[2];
  const float* emb_e = (const float*)d_in[3];
  const float* Wih_e = (const float*)d_in[4];
  const float* Whh_e = (const float*)d_in[5];
  const float* bih_e = (const float*)d_in[6];
  const float* bhh_e = (const float*)d_in[7];
  const float* emb_d = (const float*)d_in[8];
  const float* Wih_d = (const float*)d_in[9];
  const float* Whh_d = (const float*)d_in[10];
  const float* bih_d = (const float*)d_in[11];
  const float* bhh_d = (const float*)d_in[12];
  const float* Wc    = (const float*)d_in[13];
  const float* bc    = (const float*)d_in[14];
  const float* Wo    = (const float*)d_in[15];
  const float* bo    = (const float*)d_in[16];

  float* logits = (float*)d_out;
  float* attns  = (float*)d_out + (long)B_ * STEPS_ * V_;

  float* w = (float*)d_ws;
  __half* W3e  = (__half*)w;                    // 786432 halves (1.5MB)
  __half* W3d  = (__half*)(w + 393216);         // 1.5MB
  float*  zb   = w + 786432;                    // 1536 zeros (GV bias)
  float*  GIe  = w + 788480;                    // 4096 x 1536 f32
  float*  GId  = GIe + 6291456;                 // 2048 x 1536 f32
  __half* EO16 = (__half*)(GId + 3145728);      // 4MB
  float*  h0   = GId + 3145728 + 1048576;       // 32 x 512
  // overlays inside GIe (dead after encoder):
  __half* GV    = (__half*)GIe;                 // 4096 x 1536 f16
  float*  hctx  = GIe + 3145728;                // 2048 x 1024 f32
  float*  ccall = GIe + 5242880;                // 2016 x 512 f32

  hipMemsetAsync(EO16, 0, 2097152 * sizeof(__half), stream);
  hipMemsetAsync(zb, 0, 1536 * sizeof(float), stream);

  k_pack_w3<<<384, 256, 0, stream>>>(Whh_e, 512, 0, W3e);
  k_pack_w3<<<384, 256, 0, stream>>>(Whh_d, 512, 0, W3d);

  // GIe = emb_enc[src] @ Wih_e^T + bih_e   (single-pass bf16)
  k_mfma_gemm<<<dim3(1536 / 128, 4096 / 128), 256, 0, stream>>>(
      nullptr, emb_e, src, 1, Wih_e, 512, bih_e, GIe, 1536L, 32L * 1536L,
      4096, 1536, 512, 0, 1);
  // GId = emb_dec[tgt] @ Wih_d[:, :512]^T + bih_d   (single-pass bf16)
  k_mfma_gemm<<<dim3(1536 / 128, (2016 + 127) / 128), 256, 0, stream>>>(
      nullptr, emb_d, tgt, 2, Wih_d, 1024, bih_d, GId, 1536L, 32L * 1536L,
      2016, 1536, 512, 0, 1);

  k_enc_all<<<32, 1024, 0, stream>>>(GIe, W3e, bhh_e, lens, h0, EO16);

  // GV = EO16 @ Wih_d[:,512:1024]^T (f16 in/out, zero bias, single-pass)
  k_mfma_gemm<<<dim3(1536 / 128, 4096 / 128), 256, 0, stream>>>(
      (const float*)EO16, nullptr, nullptr, 3, Wih_d + 512, 1024, zb, GV,
      1536L, 49152L, 4096, 1536, 512, 2, 1);

  k_dec_all<<<32, 1024, 0, stream>>>(GId, EO16, W3d, GV, bhh_d, lens, h0,
                                     hctx, attns);

  // cc = tanh([hn|ctx] @ Wc^T + bc) (single-pass)
  k_mfma_gemm<<<dim3(512 / 128, (2016 + 127) / 128), 256, 0, stream>>>(
      hctx, nullptr, nullptr, 0, Wc, 1024, bc, ccall, 512L, 16384L,
      2016, 512, 1024, 1, 1);

  // logits = ccall @ Wo^T + bo (single-pass)
  k_mfma_gemm<<<dim3(V_ / 128, (2016 + 127) / 128), 256, 0, stream>>>(
      ccall, nullptr, nullptr, 0, Wo, 512, bo, logits,
      (long)STEPS_ * V_, (long)V_, 2016, 32000, 512, 0, 1);
}